// Round 4
// baseline (69.341 us; speedup 1.0000x reference)
//
#include <hip/hip_runtime.h>

// SSIM loss, fused, barrier-free, LDS-free hot loop.
// inputs: img1,img2 f32 (16,3,512,512); out f32[16].
//
// One wave owns a full 512-col row-strip: 8 cols/lane. Vertical sliding
// 11-row column sums for {x1,x2,x1^2,x2^2,x1*x2} in registers (a*[8]).
// Horizontal 11-window via per-lane local prefix LP[0..7] + 8 INDEPENDENT
// __shfl_down per array (no serial shuffle chains, no LDS arrays, no
// __syncthreads). New/old slide rows prefetched one iteration ahead into
// registers; old-row re-reads hit L2/L3 (whole input is L3-resident).
// Wave shfl-reduce -> atomicAdd(double) -> finalize kernel.
//
// Window algebra (lane t, cols 8t..8t+7, T = LP[7]):
//   W(8t)     = T + R1[2]
//   W(8t+j)   = T + R1[j+2] - LP[j-1]          j=1..5
//   W(8t+6/7) = (T + R1[7]) + R2[j-6] - LP[j-1]
// where R1[k] = lane(t+1).LP[k], R2[k] = lane(t+2).LP[k].

namespace {
constexpr int BATCH = 16;
constexpr int CHAN  = 3;
constexpr int HDIM  = 512;
constexpr int WDIM  = 512;
constexpr int WIN   = 11;
constexpr int HO    = HDIM - WIN + 1;   // 502
constexpr int WO    = WDIM - WIN + 1;   // 502
constexpr int STRIPS = 63;              // 8-row strips per image (last: 6)
constexpr int RPS   = 8;
constexpr int WPB   = 4;                // independent waves per block
constexpr int NTHR  = WPB * 64;
constexpr int NBLK  = BATCH * CHAN * STRIPS / WPB;  // 756
constexpr float C1F = 6.5025f;          // (0.01*255)^2
constexpr float C2F = 58.5225f;         // (0.03*255)^2
constexpr float INVW2 = 1.0f / 121.0f;
}

__device__ __forceinline__ float ssim_px(float v1, float v2, float v11,
                                         float v22, float v12) {
  float mu1 = v1 * INVW2, mu2 = v2 * INVW2;
  float mu1sq = mu1 * mu1, mu2sq = mu2 * mu2, mu12 = mu1 * mu2;
  float sig1 = fmaf(v11, INVW2, -mu1sq);
  float sig2 = fmaf(v22, INVW2, -mu2sq);
  float sg12 = fmaf(v12, INVW2, -mu12);
  float n = (2.0f * mu12 + C1F) * (2.0f * sg12 + C2F);
  float d = (mu1sq + mu2sq + C1F) * (sig1 + sig2 + C2F);
  return n * __builtin_amdgcn_rcpf(d);   // 1-ulp; threshold is 6e-5
}

__global__ __launch_bounds__(NTHR, 3) void ssim_main(
    const float* __restrict__ g1, const float* __restrict__ g2,
    double* __restrict__ ws) {
  const int t   = threadIdx.x & 63;
  const int wv  = threadIdx.x >> 6;
  const int wid = blockIdx.x * WPB + wv;
  const int img = wid / STRIPS;          // (b,c) pair, 0..47
  const int strip = wid % STRIPS;
  const int b   = img / CHAN;
  const int r0  = strip * RPS;
  const int r1  = min(r0 + RPS, HO);

  const float* __restrict__ p1 = g1 + (size_t)img * HDIM * WDIM + 8 * t;
  const float* __restrict__ p2 = g2 + (size_t)img * HDIM * WDIM + 8 * t;

  // vertical sliding column sums for this lane's 8 columns
  float a1[8], a2[8], a11[8], a22[8], a12[8];
#pragma unroll
  for (int k = 0; k < 8; ++k) a1[k] = a2[k] = a11[k] = a22[k] = a12[k] = 0.f;

  auto accum = [&](const float4& U0, const float4& U1, const float4& V0,
                   const float4& V1) {
    float uu[8] = {U0.x, U0.y, U0.z, U0.w, U1.x, U1.y, U1.z, U1.w};
    float vv[8] = {V0.x, V0.y, V0.z, V0.w, V1.x, V1.y, V1.z, V1.w};
#pragma unroll
    for (int k = 0; k < 8; ++k) {
      a1[k] += uu[k];
      a2[k] += vv[k];
      a11[k] = fmaf(uu[k], uu[k], a11[k]);
      a22[k] = fmaf(vv[k], vv[k], a22[k]);
      a12[k] = fmaf(uu[k], vv[k], a12[k]);
    }
  };
  auto desum = [&](const float4& U0, const float4& U1, const float4& V0,
                   const float4& V1) {
    float uu[8] = {U0.x, U0.y, U0.z, U0.w, U1.x, U1.y, U1.z, U1.w};
    float vv[8] = {V0.x, V0.y, V0.z, V0.w, V1.x, V1.y, V1.z, V1.w};
#pragma unroll
    for (int k = 0; k < 8; ++k) {
      a1[k] -= uu[k];
      a2[k] -= vv[k];
      a11[k] = fmaf(uu[k], -uu[k], a11[k]);
      a22[k] = fmaf(vv[k], -vv[k], a22[k]);
      a12[k] = fmaf(uu[k], -vv[k], a12[k]);
    }
  };

  // local prefix + 8 independent shuffles -> 8 window sums for one array
  auto hwin = [&](const float s[8], float* Wq) {
    float LP0 = s[0];
    float LP1 = LP0 + s[1];
    float LP2 = LP1 + s[2];
    float LP3 = LP2 + s[3];
    float LP4 = LP3 + s[4];
    float LP5 = LP4 + s[5];
    float LP6 = LP5 + s[6];
    float LP7 = LP6 + s[7];
    float R12 = __shfl_down(LP2, 1, 64);
    float R13 = __shfl_down(LP3, 1, 64);
    float R14 = __shfl_down(LP4, 1, 64);
    float R15 = __shfl_down(LP5, 1, 64);
    float R16 = __shfl_down(LP6, 1, 64);
    float R17 = __shfl_down(LP7, 1, 64);
    float R20 = __shfl_down(LP0, 2, 64);
    float R21 = __shfl_down(LP1, 2, 64);
    float TT = LP7 + R17;
    Wq[0] = LP7 + R12;
    Wq[1] = (LP7 + R13) - LP0;
    Wq[2] = (LP7 + R14) - LP1;
    Wq[3] = (LP7 + R15) - LP2;
    Wq[4] = (LP7 + R16) - LP3;
    Wq[5] = TT - LP4;
    Wq[6] = (TT + R20) - LP5;
    Wq[7] = (TT + R21) - LP6;
  };

  // warm-up: rows r0 .. r0+9
#pragma unroll 2
  for (int dy = 0; dy < WIN - 1; ++dy) {
    const float* q1 = p1 + (size_t)(r0 + dy) * WDIM;
    const float* q2 = p2 + (size_t)(r0 + dy) * WDIM;
    float4 u0 = *(const float4*)q1, u1 = *(const float4*)(q1 + 4);
    float4 v0 = *(const float4*)q2, v1 = *(const float4*)(q2 + 4);
    accum(u0, u1, v0, v1);
  }

  // preload NEW = row r0+10, OLD = row r0
  float4 nu0, nu1, nv0, nv1, ou0, ou1, ov0, ov1;
  {
    const float* q1 = p1 + (size_t)(r0 + WIN - 1) * WDIM;
    const float* q2 = p2 + (size_t)(r0 + WIN - 1) * WDIM;
    nu0 = *(const float4*)q1; nu1 = *(const float4*)(q1 + 4);
    nv0 = *(const float4*)q2; nv1 = *(const float4*)(q2 + 4);
    const float* o1 = p1 + (size_t)r0 * WDIM;
    const float* o2 = p2 + (size_t)r0 * WDIM;
    ou0 = *(const float4*)o1; ou1 = *(const float4*)(o1 + 4);
    ov0 = *(const float4*)o2; ov1 = *(const float4*)(o2 + 4);
  }

  float acc = 0.0f;
  for (int r = r0; r < r1; ++r) {
    // complete window: rows [r, r+10]
    accum(nu0, nu1, nv0, nv1);
    // prefetch next NEW (row r+11, clamped; latency hides under compute)
    {
      int rn = min(r + WIN, HDIM - 1);
      const float* q1 = p1 + (size_t)rn * WDIM;
      const float* q2 = p2 + (size_t)rn * WDIM;
      nu0 = *(const float4*)q1; nu1 = *(const float4*)(q1 + 4);
      nv0 = *(const float4*)q2; nv1 = *(const float4*)(q2 + 4);
    }

    float W0[8], W1[8], W2[8], W3[8], W4[8];
    hwin(a1,  W0);
    hwin(a2,  W1);
    hwin(a11, W2);
    hwin(a22, W3);
    hwin(a12, W4);

#pragma unroll
    for (int j = 0; j < 8; ++j) {
      float v = ssim_px(W0[j], W1[j], W2[j], W3[j], W4[j]);
      acc += (8 * t + j < WO) ? v : 0.0f;
    }

    // slide out row r; prefetch next OLD (row r+1)
    desum(ou0, ou1, ov0, ov1);
    {
      int ro = min(r + 1, HDIM - 1);
      const float* o1 = p1 + (size_t)ro * WDIM;
      const float* o2 = p2 + (size_t)ro * WDIM;
      ou0 = *(const float4*)o1; ou1 = *(const float4*)(o1 + 4);
      ov0 = *(const float4*)o2; ov1 = *(const float4*)(o2 + 4);
    }
  }

  // wave reduction, one double atomic per wave
#pragma unroll
  for (int off = 32; off > 0; off >>= 1) acc += __shfl_down(acc, off, 64);
  if (t == 0) atomicAdd(&ws[b], (double)acc);
}

__global__ void ssim_finalize(const double* __restrict__ ws,
                              float* __restrict__ out) {
  int i = threadIdx.x;
  if (i < BATCH) {
    double mean = ws[i] / ((double)CHAN * HO * WO);
    out[i] = (float)(1.0 - mean);
  }
}

extern "C" void kernel_launch(void* const* d_in, const int* in_sizes, int n_in,
                              void* d_out, int out_size, void* d_ws,
                              size_t ws_size, hipStream_t stream) {
  const float* img1 = (const float*)d_in[0];
  const float* img2 = (const float*)d_in[1];
  float* out = (float*)d_out;
  double* ws = (double*)d_ws;

  hipMemsetAsync(d_ws, 0, BATCH * sizeof(double), stream);
  ssim_main<<<dim3(NBLK), NTHR, 0, stream>>>(img1, img2, ws);
  ssim_finalize<<<1, 64, 0, stream>>>(ws, out);
}